// Round 9
// baseline (1888.602 us; speedup 1.0000x reference)
//
#include <hip/hip_runtime.h>

// LatentExpander: 2-layer LSTM (H=128), B=512, SEQ=1024, out L=64.
// Inputs fp32, OUTPUT fp32. Single persistent kernel, no workspace.
// 128 blocks x 512 threads; 4 batch rows/block at MFMA rows {0,4,8,12}.
// ALL MFMA operands fp16; fp32 accumulators/state. INTRINSIC MFMAs only.
//
// R9 vs R8 (1836us steady): LDS-pipe attack. Budget showed ~248 b128
// wave-ops/step/CU ~= 250KB through a ~100B/cy pipe ~= 2000+cy of the
// 4300cy step. 75% of A-frag traffic read garbage rows (only rows
// {0,4,8,12} are valid batch rows). Fix: A-frag lanes read row (l15 & 12)
// -- garbage lanes alias valid rows; same-address lanes BROADCAST (free).
// Every A-read (L0/L1/OP) shrinks 4x in distinct traffic; valid-row
// results bit-identical (D row m depends only on A row m).
// Also hoisted per-thread constants out of LDS: xz (2 regs), layer-1 bias
// (4 regs), out bias (1 reg) -- deletes 12 more wave-ops/step.
//
// MFMA 16x16x32 layout anchors (HW-verified; dtype-independent on gfx950):
//   A: lane holds A[m=l&15][k=(l>>4)*8+e]   (8 contig k, row-major LDS read)
//   B: lane holds B[k=(l>>4)*8+e][n=l&15]   = W[n][k], 8 contig k of row n
//   C/D: lane holds D[row=(l>>4)*4+r][col=l&15]  (r=0 -> row 4*l4)

#define DI __device__ __forceinline__

typedef float f32x4 __attribute__((ext_vector_type(4)));
typedef _Float16 h16x4 __attribute__((ext_vector_type(4)));
typedef _Float16 h16x8 __attribute__((ext_vector_type(8)));

// fast sigmoid: 1 v_exp + 1 v_rcp (+mul/add). rcp ~1ulp; error << fp16 MFMA
// rounding already present in the gates.
DI float sigm_(float x) {
  float e = __expf(-x);
  return __builtin_amdgcn_rcpf(1.0f + e);
}
// fast tanh: 2*sigmoid(2x)-1 = 2*rcp(1+exp(-2x))-1. Overflow-safe:
// exp(-2x)->inf => rcp(inf)=0 => -1 exactly.
DI float tanh_(float x) {
  float e = __expf(-2.0f * x);
  return __builtin_fmaf(2.0f, __builtin_amdgcn_rcpf(1.0f + e), -1.0f);
}
// load 8 consecutive fp32, round (RNE) to fp16 frag
DI h16x8 cvt8h(const float* __restrict__ p) {
  f32x4 a = *(const f32x4*)p;
  f32x4 b = *(const f32x4*)(p + 4);
  _Float16 t[8];
#pragma unroll
  for (int i = 0; i < 4; ++i) {
    t[i]     = (_Float16)a[i];
    t[4 + i] = (_Float16)b[i];
  }
  return *(h16x8*)t;
}

// ---------------- LDS map (bytes) ----------------
// H0: 2 bufs x 16 rows x 400 B (cols 0..127 h0, 128..191 h_prev) = 12800
// H1: 2 bufs x 16 x 272 = 8704                          [12800, 21504)
// WO: out-proj B-frag stream, 16 frags x 64 lanes x 16 = [21504, 37888)
// AZ: prologue z-tile 16 x 528 = 8448 (prologue only)   [37888, 46336)
// OB: out ring, 2 steps x 4 rows x 64 f32 = 2048        [46336, 48384)
// WL: LDS weight frags, 8 waves x 12 slots x 64 x 16    [48384, 146688)
//     slots 0..3 = L0 kc5 (g=0..3); 4..7 = L1 kc6; 8..11 = L1 kc7
#define L_H0 0
#define L_H1 12800
#define L_WO 21504
#define L_AZ 37888
#define L_OB 46336
#define L_WL 48384
#define L_TOT 146688
static_assert(L_TOT <= 163840, "LDS budget (160 KiB/CU)");

// One time step; P = ping-pong phase (compile-time -> immediate LDS bases).
template <int P>
DI void lstm_step(unsigned char* smem,
                  const h16x8 (&wf0)[20], const h16x8 (&wf1)[24],
                  float& c0r, float& c1r, h16x4 xzr, f32x4 bvr, float bo,
                  int a0off, int a1off, int v16, int wlb,
                  int w0off, int w1off, int oboff, int obro,
                  int col, int wv, int t, float* outp0) {
  constexpr int h0r = L_H0 + P * 6400, h0w = L_H0 + 6400 - P * 6400;
  constexpr int h1r = L_H1 + P * 4352, h1w = L_H1 + 4352 - P * 4352;

  // === layer 0: gates = [h0_old | h_prev] x W + xz ===
  f32x4 acc[4];
#pragma unroll
  for (int g = 0; g < 4; ++g) {
    float v = (float)xzr[g];
    f32x4 a = {v, v, v, v};                          // garbage rows: finite
    acc[g] = a;
  }
#pragma unroll
  for (int kc = 0; kc < 6; ++kc) {
    // broadcast A-read: lane reads row (l15&12) -- garbage lanes alias
    // valid rows; same-address lanes are a free LDS broadcast.
    h16x8 af = *(const h16x8*)(smem + h0r + a0off + kc * 64);
#pragma unroll
    for (int g = 0; g < 4; ++g) {
      h16x8 bf = (kc < 5)
          ? wf0[kc * 4 + g]
          : *(const h16x8*)(smem + wlb + g * 1024);          // slots 0..3
      acc[g] = __builtin_amdgcn_mfma_f32_16x16x32_f16(af, bf, acc[g], 0, 0, 0);
    }
  }
  {  // epilogue: ONE element (row 4*l4, col)
    float ig = sigm_(acc[0][0]), fg = sigm_(acc[1][0]);
    float gg = tanh_(acc[2][0]), og = sigm_(acc[3][0]);
    c0r = fg * c0r + ig * gg;
    *(_Float16*)(smem + h0w + w0off) = (_Float16)(og * tanh_(c0r));
  }
  __syncthreads();                              // h0(t) visible

  // === layer 1: gates = [h0_new | h1_old] x W + (b_ih1+b_hh1) ===
  // kc 0..5 B-frags from registers; kc 6,7 from LDS (slots 4..11).
#pragma unroll
  for (int g = 0; g < 4; ++g) {
    f32x4 a = {bvr[g], bvr[g], bvr[g], bvr[g]};
    acc[g] = a;
  }
#pragma unroll
  for (int kc = 0; kc < 8; ++kc) {
    h16x8 af = (kc < 4)
        ? *(const h16x8*)(smem + h0w + a0off + kc * 64)
        : *(const h16x8*)(smem + h1r + a1off + (kc - 4) * 64);
#pragma unroll
    for (int g = 0; g < 4; ++g) {
      h16x8 bf = (kc < 6)
          ? wf1[kc * 4 + g]
          : *(const h16x8*)(smem + wlb + ((kc - 6) * 4 + g + 4) * 1024);
      acc[g] = __builtin_amdgcn_mfma_f32_16x16x32_f16(af, bf, acc[g], 0, 0, 0);
    }
  }
  {  // epilogue: ONE element
    float ig = sigm_(acc[0][0]), fg = sigm_(acc[1][0]);
    float gg = tanh_(acc[2][0]), og = sigm_(acc[3][0]);
    c1r = fg * c1r + ig * gg;
    *(_Float16*)(smem + h1w + w1off) = (_Float16)(og * tanh_(c1r));
  }
  __syncthreads();                              // h1(t) visible

  // === out-proj (waves 0-3): h_t = tanh(h1_new x W_out^T + b_out) ===
  // writes LDS only: OB ring (4 rows x 64 f32) + h_prev fp16.
  if (wv < 4) {
    f32x4 ao = {bo, bo, bo, bo};
#pragma unroll
    for (int kc = 0; kc < 4; ++kc) {
      h16x8 af  = *(const h16x8*)(smem + h1w + a1off + kc * 64);
      h16x8 bfr = *(const h16x8*)(smem + L_WO + kc * 4096 + v16);
      ao = __builtin_amdgcn_mfma_f32_16x16x32_f16(af, bfr, ao, 0, 0, 0);
    }
    float v = tanh_(ao[0]);                     // ONE element (row 4*l4)
    *(float*)(smem + L_OB + P * 1024 + oboff) = v;          // out ring
    *(_Float16*)(smem + h0w + w0off + 256) = (_Float16)v;   // h_prev(t)
  }
  __syncthreads();                              // h_prev(t) + OB visible

  // === coalesced flush every other step: 2 t-steps x 4 rows x 64 j ===
  // thread tid -> (p2=tid>>8, row=(tid>>6)&3, j=tid&63); 256B runs.
  if (P) {
    float vv = *(const float*)(smem + L_OB + obro);
    *(outp0 + (unsigned)(t - 1) * 64u) = vv;    // outp0 includes +p2*64
  }
}

__global__ __launch_bounds__(512, 2) void k_main(
    const float* __restrict__ z,
    const float* __restrict__ W_init_h, const float* __restrict__ b_init_h,
    const float* __restrict__ W_init_c, const float* __restrict__ b_init_c,
    const float* __restrict__ W_ih0, const float* __restrict__ W_hh0,
    const float* __restrict__ b_ih0, const float* __restrict__ b_hh0,
    const float* __restrict__ W_ih1, const float* __restrict__ W_hh1,
    const float* __restrict__ b_ih1, const float* __restrict__ b_hh1,
    const float* __restrict__ W_out, const float* __restrict__ b_out,
    float* __restrict__ out) {
  __shared__ __align__(16) unsigned char smem[L_TOT];
  const int tid = threadIdx.x;
  const int w = tid >> 6, l = tid & 63;
  const int l15 = l & 15, l4 = l >> 4;
  const int bl = blockIdx.x, b0i = bl << 2;     // 4 batch rows/block
  const int col = 16 * w + l15;                 // owned gate/hidden col 0..127

  // ---------- prologue stage 1: fills ----------
  {
    // z tile -> AZ fp16: MFMA rows 4k get z[b0+k]; other rows zero.
    int zm = tid >> 5, zk = (tid & 31) * 8;
    h16x8 zv;
    if ((zm & 3) == 0) {
      zv = cvt8h(z + (b0i + (zm >> 2)) * 256 + zk);
    } else {
      _Float16 t[8] = {};
      zv = *(h16x8*)t;
    }
    *(h16x8*)(smem + L_AZ + zm * 528 + zk * 2) = zv;
    // W_out -> per-wave frag stream: frag f=kc*4+wv, lane l holds
    // W_out[n=16*wv+(l&15)][k=kc*32+(l>>4)*8 .. +8]
    for (int i = tid; i < 1024; i += 512) {
      int li = i & 63, f = i >> 6;
      int kc = f >> 2, wv = f & 3;
      int n = 16 * wv + (li & 15), k0 = kc * 32 + ((li >> 4) & 3) * 8;
      *(h16x8*)(smem + L_WO + i * 16) = cvt8h(W_out + n * 128 + k0);
    }
    // WL: 12 LDS weight slots for this wave.
    //   f 0..3:  L0 kc5, g=f     -> W_ih0[n][32+l4*8 ..]   (k0=160..191)
    //   f 4..11: L1 kc6/7, g=f&3 -> W_hh1[n][kc*32+l4*8-128]
#pragma unroll
    for (int f = 0; f < 12; ++f) {
      int g = f & 3;
      int n = g * 128 + col;
      const float* src;
      if (f < 4) {
        src = W_ih0 + n * 320 + (32 + l4 * 8);
      } else {
        int kc = 6 + ((f - 4) >> 2);
        src = W_hh1 + n * 128 + (kc * 32 + l4 * 8 - 128);
      }
      *(h16x8*)(smem + L_WL + ((w * 12 + f) * 64 + l) * 16) = cvt8h(src);
    }
    // zero h_prev cols (128..191) of H0 buffer 0 — ALL 16 rows (finite)
    if (tid < 256) {
      int r2 = tid >> 4, c2 = (tid & 15) * 4;
      h16x4 zz = {(_Float16)0, (_Float16)0, (_Float16)0, (_Float16)0};
      *(h16x4*)(smem + L_H0 + r2 * 400 + 256 + c2 * 2) = zz;
    }
  }
  // per-thread-constant biases -> registers (no LDS)
  f32x4 bvr;
#pragma unroll
  for (int g = 0; g < 4; ++g)
    bvr[g] = b_ih1[g * 128 + col] + b_hh1[g * 128 + col];
  float bo = (w < 4) ? b_out[col] : 0.0f;
  __syncthreads();                              // AZ / WO / WL visible

  // ---------- prologue stage 2: MFMA prep GEMMs (reads AZ) ----------
  // xz[m][n] = z[m,:]·W_ih0[n,64:] + b_ih0[n]+b_hh0[n]   (n = g*128+col)
  // h/c init[m][layer*128+col] = z[m,:]·W_init_{h,c}[n,:] + b
  float c0i, c1i;
  h16x4 xzr;
  {
    f32x4 xza[4], ha[2], ca[2];
#pragma unroll
    for (int g = 0; g < 4; ++g) {
      float b = b_ih0[g * 128 + col] + b_hh0[g * 128 + col];
      f32x4 a = {b, b, b, b}; xza[g] = a;
    }
#pragma unroll
    for (int layer = 0; layer < 2; ++layer) {
      float bh = b_init_h[layer * 128 + col];
      float bc = b_init_c[layer * 128 + col];
      f32x4 ah = {bh, bh, bh, bh}; ha[layer] = ah;
      f32x4 ac = {bc, bc, bc, bc}; ca[layer] = ac;
    }
#pragma unroll
    for (int kc = 0; kc < 8; ++kc) {
      h16x8 az = *(const h16x8*)(smem + L_AZ + l15 * 528 + kc * 64 + l4 * 16);
      int kofs = kc * 32 + l4 * 8;
#pragma unroll
      for (int g = 0; g < 4; ++g) {
        h16x8 bz = cvt8h(W_ih0 + (g * 128 + col) * 320 + 64 + kofs);
        xza[g] = __builtin_amdgcn_mfma_f32_16x16x32_f16(az, bz, xza[g], 0, 0, 0);
      }
#pragma unroll
      for (int layer = 0; layer < 2; ++layer) {
        h16x8 bh = cvt8h(W_init_h + (layer * 128 + col) * 256 + kofs);
        ha[layer] = __builtin_amdgcn_mfma_f32_16x16x32_f16(az, bh, ha[layer], 0, 0, 0);
        h16x8 bc = cvt8h(W_init_c + (layer * 128 + col) * 256 + kofs);
        ca[layer] = __builtin_amdgcn_mfma_f32_16x16x32_f16(az, bc, ca[layer], 0, 0, 0);
      }
    }
    // h-init -> H0/H1 buffer 0, ALL 4 r rows (garbage rows finite, never
    // read under broadcast addressing); c/xz: valid element only (r=0).
#pragma unroll
    for (int r = 0; r < 4; ++r) {
      int m = l4 * 4 + r;
      *(_Float16*)(smem + L_H0 + m * 400 + col * 2) = (_Float16)ha[0][r];
      *(_Float16*)(smem + L_H1 + m * 272 + col * 2) = (_Float16)ha[1][r];
    }
    c0i = ca[0][0]; c1i = ca[1][0];
    _Float16 t[4];
#pragma unroll
    for (int g = 0; g < 4; ++g) t[g] = (_Float16)xza[g][0];
    xzr = *(h16x4*)t;
  }

  // ---------- persistent weights -> register B-frags (fp16) ----------
  // L0 kc0..4 (K=160 of 192): k<128 -> W_hh0[n][k]; k in [128,160) -> W_ih0
  // L1 kc0..5 (K=192 of 256): k<128 -> W_ih1[n][k]; k in [128,192) -> W_hh1
  // 44 frags = 176 regs; total demand ~225 <= 256 -> honest fit, no spills.
  h16x8 wf0[20], wf1[24];
#pragma unroll
  for (int kc = 0; kc < 5; ++kc)
#pragma unroll
    for (int g = 0; g < 4; ++g) {
      int n = g * 128 + col, k0 = kc * 32 + l4 * 8;
      const float* src = (k0 < 128) ? (W_hh0 + n * 128 + k0)
                                    : (W_ih0 + n * 320 + (k0 - 128));
      wf0[kc * 4 + g] = cvt8h(src);
    }
#pragma unroll
  for (int kc = 0; kc < 6; ++kc)
#pragma unroll
    for (int g = 0; g < 4; ++g) {
      int n = g * 128 + col, k0 = kc * 32 + l4 * 8;
      const float* src = (k0 < 128) ? (W_ih1 + n * 128 + k0)
                                    : (W_hh1 + n * 128 + (k0 - 128));
      wf1[kc * 4 + g] = cvt8h(src);
    }

  float c0r = c0i, c1r = c1i;

  // per-lane LDS offsets (affine in tid — cheap for regalloc to remat)
  // A-frag reads use BROADCAST rows: l15 -> (l15 & 12); garbage lanes
  // alias valid rows (free same-address LDS broadcast, 4x less traffic).
  const int a0off = (l15 & 12) * 400 + l4 * 16; // A-frag read within H0 buf
  const int a1off = (l15 & 12) * 272 + l4 * 16; // A-frag read within H1 buf
  const int v16   = tid * 16;                   // WO frag read
  const int wlb   = L_WL + (w * 12 * 64 + l) * 16;  // WL frag base (+slot*1024)
  const int w0off = (4 * l4) * 400 + col * 2;   // h0 write (row 4*l4)
  const int w1off = (4 * l4) * 272 + col * 2;   // h1 write (row 4*l4)
  const int oboff = l4 * 256 + col * 4;         // OB write (+P*1024)
  const int obro  = (tid >> 8) * 1024 + ((tid >> 6) & 3) * 256 + (tid & 63) * 4;
  // flush: thread -> (p2, row, j); outp0 bakes in row, j, p2's time offset
  float* outp0 = out + (unsigned long long)(b0i + ((tid >> 6) & 3)) * 65536ull +
                 (tid >> 8) * 64 + (tid & 63);
  __syncthreads();                              // h-init visible

  // ---------- time loop (unrolled x2: compile-time ping-pong) ----------
  for (int t2 = 0; t2 < 1024; t2 += 2) {
    lstm_step<0>(smem, wf0, wf1, c0r, c1r, xzr, bvr, bo, a0off, a1off, v16,
                 wlb, w0off, w1off, oboff, obro, col, w, t2, outp0);
    lstm_step<1>(smem, wf0, wf1, c0r, c1r, xzr, bvr, bo, a0off, a1off, v16,
                 wlb, w0off, w1off, oboff, obro, col, w, t2 + 1, outp0);
  }
}

// ---------------- launch ----------------
extern "C" void kernel_launch(void* const* d_in, const int* in_sizes, int n_in,
                              void* d_out, int out_size, void* d_ws, size_t ws_size,
                              hipStream_t stream) {
  (void)in_sizes; (void)n_in; (void)out_size; (void)d_ws; (void)ws_size;
  const float* z        = (const float*)d_in[0];
  // d_in[1] = seq_len (int scalar) == 1024, hardcoded
  const float* W_init_h = (const float*)d_in[2];
  const float* b_init_h = (const float*)d_in[3];
  const float* W_init_c = (const float*)d_in[4];
  const float* b_init_c = (const float*)d_in[5];
  const float* W_ih0 = (const float*)d_in[6];
  const float* W_hh0 = (const float*)d_in[7];
  const float* b_ih0 = (const float*)d_in[8];
  const float* b_hh0 = (const float*)d_in[9];
  const float* W_ih1 = (const float*)d_in[10];
  const float* W_hh1 = (const float*)d_in[11];
  const float* b_ih1 = (const float*)d_in[12];
  const float* b_hh1 = (const float*)d_in[13];
  const float* W_out = (const float*)d_in[14];
  const float* b_out = (const float*)d_in[15];
  float* out = (float*)d_out;

  k_main<<<dim3(128), dim3(512), 0, stream>>>(
      z, W_init_h, b_init_h, W_init_c, b_init_c,
      W_ih0, W_hh0, b_ih0, b_hh0, W_ih1, W_hh1, b_ih1, b_hh1,
      W_out, b_out, out);
}